// Round 4
// baseline (1177.840 us; speedup 1.0000x reference)
//
#include <hip/hip_runtime.h>

#define U_NUM   100000
#define I_NUM   50000
#define FCT     64
#define NEDGE   3200000
#define BATCH   16384
#define NROWS   (U_NUM + I_NUM)      // 150000
#define TOTSLOTS (2 * NEDGE)         // 6400000

#define BSH 7                        // 128 rows per bucket
#define NBU 782                      // ceil(100000/128)
#define NBI 391                      // ceil(50000/128)
#define NBUCK (NBU + NBI)            // 1173
#define CPAD 16

__device__ __forceinline__ unsigned short f2b(float f) {
    unsigned int x = __float_as_uint(f);
    unsigned int r = (x + 0x7FFFu + ((x >> 16) & 1u)) >> 16;   // RNE
    return (unsigned short)r;
}
__device__ __forceinline__ float b2f(unsigned short u) {
    return __uint_as_float(((unsigned int)u) << 16);
}

// ---------------- fp32 -> bf16 table conversion ----------------
__global__ void conv_kernel(const float* __restrict__ in, unsigned short* __restrict__ out, int n4) {
    int t = blockIdx.x * blockDim.x + threadIdx.x;
    if (t >= n4) return;
    float4 v = *reinterpret_cast<const float4*>(in + (size_t)t * 4);
    ushort4 o;
    o.x = f2b(v.x); o.y = f2b(v.y); o.z = f2b(v.z); o.w = f2b(v.w);
    *reinterpret_cast<ushort4*>(out + (size_t)t * 4) = o;
}

// ---------------- per-row histogram ----------------
__global__ void hist_kernel(const int* __restrict__ eu, const int* __restrict__ ei,
                            int* __restrict__ cnt) {
    int t = blockIdx.x * blockDim.x + threadIdx.x;
    if (t >= NEDGE) return;
    atomicAdd(&cnt[eu[t]], 1);
    atomicAdd(&cnt[U_NUM + ei[t]], 1);
}

// ---------------- exclusive scan over NROWS (3 kernels) ----------------
__global__ void scan1_kernel(const int* __restrict__ cnt, int* __restrict__ out,
                             int* __restrict__ bsum) {
    __shared__ int s[256];
    int t = threadIdx.x;
    int base = blockIdx.x * 1024 + t * 4;
    int v[4];
#pragma unroll
    for (int k = 0; k < 4; k++) v[k] = (base + k < NROWS) ? cnt[base + k] : 0;
    int tot = v[0] + v[1] + v[2] + v[3];
    s[t] = tot;
    __syncthreads();
    for (int off = 1; off < 256; off <<= 1) {
        int x = (t >= off) ? s[t - off] : 0;
        __syncthreads();
        s[t] += x;
        __syncthreads();
    }
    int p = s[t] - tot;
#pragma unroll
    for (int k = 0; k < 4; k++) {
        if (base + k < NROWS) out[base + k] = p;
        p += v[k];
    }
    if (t == 255) bsum[blockIdx.x] = s[255];
}

__global__ void scan2_kernel(int* __restrict__ bsum, int nb) {
    __shared__ int s[256];
    int t = threadIdx.x;
    int v = (t < nb) ? bsum[t] : 0;
    s[t] = v;
    __syncthreads();
    for (int off = 1; off < 256; off <<= 1) {
        int x = (t >= off) ? s[t - off] : 0;
        __syncthreads();
        s[t] += x;
        __syncthreads();
    }
    if (t < nb) bsum[t] = s[t] - v;
}

__global__ void scan3_kernel(int* __restrict__ rowptr, const int* __restrict__ bsum) {
    int i = blockIdx.x * blockDim.x + threadIdx.x;
    if (i < NROWS) rowptr[i] += bsum[i >> 10];
    if (i == NROWS) rowptr[NROWS] = TOTSLOTS;
}

// ---------------- phase A: XCD-class-partitioned append into bucket regions ----------------
// Ownership class = bucket & 7; block b only appends for buckets with class == b & 7.
// With round-robin block->XCD dispatch, each staging line's writers live on ONE XCD,
// so lines fill in that XCD's L2 and write back once (kills partial-line writeback amp).
__global__ void __launch_bounds__(256) xscatter_kernel(
        const int* __restrict__ eu, const int* __restrict__ ei,
        const float* __restrict__ vui, const float* __restrict__ viu,
        const int* __restrict__ rowptr, int* __restrict__ bfill,
        int2* __restrict__ staging) {
    int cls = blockIdx.x & 7;
    int sub = blockIdx.x >> 3;           // 0..255
    for (int t = sub * 256 + (int)threadIdx.x; t < NEDGE; t += 256 * 256) {
        int u = eu[t], i = ei[t];
        int bu = u >> BSH;
        if ((bu & 7) == cls) {
            int slot = rowptr[bu << BSH] + atomicAdd(&bfill[bu * CPAD], 1);
            staging[slot] = make_int2(((u & 127) << 17) | i, __float_as_int(vui[t]));
        }
        int bid = NBU + (i >> BSH);
        if ((bid & 7) == cls) {
            int slot = rowptr[U_NUM + ((i >> BSH) << BSH)] + atomicAdd(&bfill[bid * CPAD], 1);
            staging[slot] = make_int2(((i & 127) << 17) | u, __float_as_int(viu[t]));
        }
    }
}

// ---------------- phase B: per-bucket re-scatter into exact row-CSR order ----------------
__global__ void __launch_bounds__(256) rsort_kernel(const int* __restrict__ rowptr,
                                                    const int2* __restrict__ staging,
                                                    int2* __restrict__ csr) {
    __shared__ int fillr[128];
    __shared__ int rp[129];
    int b = blockIdx.x;
    int gRowBase, rows;
    if (b < NBU) {
        gRowBase = b << BSH;
        rows = min(128, U_NUM - gRowBase);
    } else {
        int rb = (b - NBU) << BSH;
        gRowBase = U_NUM + rb;
        rows = min(128, I_NUM - rb);
    }
    for (int t = threadIdx.x; t < rows; t += 256) fillr[t] = 0;
    for (int t = threadIdx.x; t <= rows; t += 256) rp[t] = rowptr[gRowBase + t];
    __syncthreads();
    int beg = rp[0], end = rp[rows];
    for (int e = beg + threadIdx.x; e < end; e += 256) {
        int2 pk = staging[e];
        int off = pk.x >> 17;
        int src = pk.x & 0x1FFFF;
        int dst = rp[off] + atomicAdd(&fillr[off], 1);
        csr[dst] = make_int2(src, pk.y);
    }
}

// ---------------- propagation stage: wave per row, register accumulate ----------------
__global__ void __launch_bounds__(256) agg_kernel(
        const unsigned short* __restrict__ uprev, const unsigned short* __restrict__ iprev,
        unsigned short* __restrict__ unext, unsigned short* __restrict__ inext,
        const float* __restrict__ di, const float* __restrict__ dj,
        const int* __restrict__ rowptr, const int2* __restrict__ csr) {
    int wid = (blockIdx.x * 256 + threadIdx.x) >> 6;
    int lane = threadIdx.x & 63;
    if (wid >= NROWS) return;
    const unsigned short* selfP;
    const unsigned short* srcT;
    unsigned short* dst;
    float dscale;
    if (wid < U_NUM) {
        selfP = uprev + (size_t)wid * FCT;
        srcT = iprev;
        dst = unext + (size_t)wid * FCT;
        dscale = di[wid];
    } else {
        int r = wid - U_NUM;
        selfP = iprev + (size_t)r * FCT;
        srcT = uprev;
        dst = inext + (size_t)r * FCT;
        dscale = dj[r];
    }
    int beg = rowptr[wid], end = rowptr[wid + 1];
    float acc = b2f(selfP[lane]) * dscale;
    int e = beg;
    for (; e + 8 <= end; e += 8) {
        int2 p[8];
        float g[8];
#pragma unroll
        for (int k = 0; k < 8; k++) p[k] = csr[e + k];
#pragma unroll
        for (int k = 0; k < 8; k++) g[k] = b2f(srcT[(size_t)p[k].x * FCT + lane]);
#pragma unroll
        for (int k = 0; k < 8; k++) acc = fmaf(__int_as_float(p[k].y), g[k], acc);
    }
    for (; e < end; ++e) {
        int2 p = csr[e];
        acc = fmaf(__int_as_float(p.y), b2f(srcT[(size_t)p.x * FCT + lane]), acc);
    }
    dst[lane] = f2b(acc);
}

// ---------------- BPR head ----------------
__global__ void __launch_bounds__(256) batch_kernel(
        const float* __restrict__ u0f, const float* __restrict__ i0f,
        const unsigned short* __restrict__ u1, const unsigned short* __restrict__ u2,
        const unsigned short* __restrict__ u3,
        const unsigned short* __restrict__ i1, const unsigned short* __restrict__ i2,
        const unsigned short* __restrict__ i3,
        const int* __restrict__ user, const int* __restrict__ ita, const int* __restrict__ itb,
        float* __restrict__ out, float* __restrict__ ls, float* __restrict__ l2a) {
    int wid = (blockIdx.x * 256 + threadIdx.x) >> 6;
    int lane = threadIdx.x & 63;
    if (wid >= BATCH) return;
    size_t uo = (size_t)user[wid] * FCT + lane;
    size_t ao = (size_t)ita[wid] * FCT + lane;
    size_t bo = (size_t)itb[wid] * FCT + lane;

    float pi, pj, l2;
    {
        float ue = u0f[uo], ie = i0f[ao], je = i0f[bo];
        pi = ue * ie; pj = ue * je; l2 = ue * ue + ie * ie + je * je;
    }
    const unsigned short* Ut[3] = {u1, u2, u3};
    const unsigned short* It[3] = {i1, i2, i3};
#pragma unroll
    for (int l = 0; l < 3; l++) {
        float ue = b2f(Ut[l][uo]), ie = b2f(It[l][ao]), je = b2f(It[l][bo]);
        pi += ue * ie;
        pj += ue * je;
        l2 += ue * ue + ie * ie + je * je;
    }
#pragma unroll
    for (int off = 32; off; off >>= 1) {
        pi += __shfl_xor(pi, off);
        pj += __shfl_xor(pj, off);
        l2 += __shfl_xor(l2, off);
    }
    if (lane == 0) {
        out[wid] = pi;
        out[BATCH + wid] = pj;
        float x = pi - pj;
        ls[wid] = fminf(x, 0.0f) - log1pf(expf(-fabsf(x)));
        l2a[wid] = 0.01f * l2;
    }
}

__global__ void final_kernel(const float* __restrict__ ls, const float* __restrict__ l2a,
                             float* __restrict__ out) {
    __shared__ float s1[256], s2[256];
    int t = threadIdx.x;
    float a = 0.f, b = 0.f;
    for (int i = t; i < BATCH; i += 256) {
        a += ls[i];
        b += l2a[i];
    }
    s1[t] = a;
    s2[t] = b;
    __syncthreads();
    for (int off = 128; off; off >>= 1) {
        if (t < off) {
            s1[t] += s1[t + off];
            s2[t] += s2[t + off];
        }
        __syncthreads();
    }
    if (t == 0) {
        float loss2 = -s1[0] / (float)BATCH;
        float l2m = s2[0] / (float)BATCH;
        out[2 * BATCH] = loss2 + l2m;
        out[2 * BATCH + 1] = loss2;
    }
}

// ---------------- launch ----------------
extern "C" void kernel_launch(void* const* d_in, const int* in_sizes, int n_in,
                              void* d_out, int out_size, void* d_ws, size_t ws_size,
                              hipStream_t stream) {
    const float* u0f = (const float*)d_in[0];
    const float* i0f = (const float*)d_in[1];
    const float* di  = (const float*)d_in[2];
    const float* dj  = (const float*)d_in[3];
    const float* vui = (const float*)d_in[4];
    const float* viu = (const float*)d_in[5];
    const int*   eu  = (const int*)d_in[6];
    const int*   ei  = (const int*)d_in[7];
    const int*   usr = (const int*)d_in[8];
    const int*   ita = (const int*)d_in[9];
    const int*   itb = (const int*)d_in[10];
    float* out = (float*)d_out;

    char* p = (char*)d_ws;
    auto alloc = [&](size_t bytes) -> char* {
        char* r = p;
        p += (bytes + 255) & ~(size_t)255;
        return r;
    };
    unsigned short* u0b = (unsigned short*)alloc((size_t)U_NUM * FCT * 2);
    unsigned short* u1b = (unsigned short*)alloc((size_t)U_NUM * FCT * 2);
    unsigned short* i0b = (unsigned short*)alloc((size_t)I_NUM * FCT * 2);
    unsigned short* i1b = (unsigned short*)alloc((size_t)I_NUM * FCT * 2);
    int2* csr     = (int2*)alloc((size_t)TOTSLOTS * 8);
    int2* staging = (int2*)alloc((size_t)TOTSLOTS * 8);
    int* rowptr = (int*)alloc((size_t)(NROWS + 1) * 4);
    int* cnt    = (int*)alloc((size_t)NROWS * 4);
    int* bsum   = (int*)alloc(256 * 4);
    int* bfill  = (int*)alloc((size_t)NBUCK * CPAD * 4);
    float* ls   = (float*)alloc((size_t)BATCH * 4);
    float* l2a  = (float*)alloc((size_t)BATCH * 4);
    // overlay levels 2,3 on the staging buffer (staging dead after rsort)
    unsigned short* u2b = (unsigned short*)staging;
    unsigned short* u3b = u2b + (size_t)U_NUM * FCT;
    unsigned short* i2b = u3b + (size_t)U_NUM * FCT;
    unsigned short* i3b = i2b + (size_t)I_NUM * FCT;

    hipMemsetAsync(cnt, 0, (size_t)NROWS * 4, stream);
    hipMemsetAsync(bfill, 0, (size_t)NBUCK * CPAD * 4, stream);

    conv_kernel<<<(U_NUM * FCT / 4 + 255) / 256, 256, 0, stream>>>(u0f, u0b, U_NUM * FCT / 4);
    conv_kernel<<<(I_NUM * FCT / 4 + 255) / 256, 256, 0, stream>>>(i0f, i0b, I_NUM * FCT / 4);

    hist_kernel<<<(NEDGE + 255) / 256, 256, 0, stream>>>(eu, ei, cnt);
    int nb = (NROWS + 1023) / 1024;
    scan1_kernel<<<nb, 256, 0, stream>>>(cnt, rowptr, bsum);
    scan2_kernel<<<1, 256, 0, stream>>>(bsum, nb);
    scan3_kernel<<<(NROWS + 1 + 255) / 256, 256, 0, stream>>>(rowptr, bsum);

    xscatter_kernel<<<2048, 256, 0, stream>>>(eu, ei, vui, viu, rowptr, bfill, staging);
    rsort_kernel<<<NBUCK, 256, 0, stream>>>(rowptr, staging, csr);

    int aggGrid = (NROWS * 64) / 256 + 1;
    agg_kernel<<<aggGrid, 256, 0, stream>>>(u0b, i0b, u1b, i1b, di, dj, rowptr, csr);
    agg_kernel<<<aggGrid, 256, 0, stream>>>(u1b, i1b, u2b, i2b, di, dj, rowptr, csr);
    agg_kernel<<<aggGrid, 256, 0, stream>>>(u2b, i2b, u3b, i3b, di, dj, rowptr, csr);

    batch_kernel<<<(BATCH * 64) / 256, 256, 0, stream>>>(u0f, i0f, u1b, u2b, u3b,
                                                         i1b, i2b, i3b,
                                                         usr, ita, itb, out, ls, l2a);
    final_kernel<<<1, 256, 0, stream>>>(ls, l2a, out);
}